// Round 1
// baseline (72.684 us; speedup 1.0000x reference)
//
#include <hip/hip_runtime.h>
#include <stdint.h>

// out[m,p] = sum_k f32(bits(x[m,k]) + bits(weight[p,k]) - OFFSET) + bias[p]
// m=256, n=512, p=512. Pure VALU workload (uint add on bit patterns -> no MFMA).

#define OFFSET_FP32 1064828928u

constexpr int M = 256;
constexpr int N = 512;
constexpr int P = 512;

constexpr int BM = 4;    // m rows per block
constexpr int BP = 128;  // p cols per block
constexpr int KT = 64;   // k tile

// grid: (P/BP=4, M/BM=64) = 256 blocks, 256 threads (4 waves) each -> 1024 waves.
__global__ __launch_bounds__(256) void lmul_linear_kernel(
    const uint32_t* __restrict__ xb,   // [M][N] bit patterns of x
    const uint32_t* __restrict__ wb,   // [P][N] bit patterns of weight
    const float*    __restrict__ bias, // [P]
    float*          __restrict__ out)  // [M][P]
{
    // +1 pad: staging writes Bs[wk][pp] stride 129 words -> 2 lanes/bank (free);
    // inner reads Bs[kk][p_local] consecutive -> 2 lanes/bank (free).
    __shared__ uint32_t Bs[KT][BP + 1];

    const int tid     = threadIdx.x;
    const int p_local = tid & (BP - 1);  // 0..127
    const int m_local = tid >> 7;        // 0..1 (each thread owns 2 m rows)

    const int p0 = blockIdx.x * BP;
    const int m0 = blockIdx.y * BM + m_local * 2;
    const int p  = p0 + p_local;

    const uint32_t* xrow0 = xb + (size_t)m0 * N;
    const uint32_t* xrow1 = xb + (size_t)(m0 + 1) * N;

    float acc0 = 0.0f, acc1 = 0.0f;

    // staging decomposition: 256 threads cover 64k x 4p per pass
    const int wk  = tid & (KT - 1);  // 0..63, coalesced along k (n axis of weight)
    const int wp4 = tid >> 6;        // 0..3

    for (int k0 = 0; k0 < N; k0 += KT) {
        // Stage B tile transposed, folding the -OFFSET correction in here
        // (0.5 ops per k per thread instead of 2 per k in the inner loop).
        #pragma unroll
        for (int j = 0; j < BP / 4; ++j) {
            const int pp = wp4 + j * 4;
            Bs[wk][pp] = wb[(size_t)(p0 + pp) * N + (k0 + wk)] - OFFSET_FP32;
        }
        __syncthreads();

        // Inner: 1 ds_read + 2 wave-uniform global loads (L1 broadcast,
        // vectorize across kk when unrolled) + 4 VALU adds per kk.
        #pragma unroll 16
        for (int kk = 0; kk < KT; ++kk) {
            const uint32_t b  = Bs[kk][p_local];
            const uint32_t a0 = xrow0[k0 + kk];
            const uint32_t a1 = xrow1[k0 + kk];
            acc0 += __uint_as_float(a0 + b);
            acc1 += __uint_as_float(a1 + b);
        }
        __syncthreads();
    }

    const float bv = bias[p];
    out[(size_t)m0 * P + p]       = acc0 + bv;
    out[(size_t)(m0 + 1) * P + p] = acc1 + bv;
}

extern "C" void kernel_launch(void* const* d_in, const int* in_sizes, int n_in,
                              void* d_out, int out_size, void* d_ws, size_t ws_size,
                              hipStream_t stream) {
    const uint32_t* xb   = (const uint32_t*)d_in[0];  // x: (256,512) f32 bits
    const uint32_t* wb   = (const uint32_t*)d_in[1];  // weight: (512,512) f32 bits
    const float*    bias = (const float*)d_in[2];     // (512,)
    float*          out  = (float*)d_out;             // (256,512) f32

    dim3 grid(P / BP, M / BM);  // (4, 64) = 256 blocks
    dim3 block(256);
    lmul_linear_kernel<<<grid, block, 0, stream>>>(xb, wb, bias, out);
}

// Round 2
// 70.726 us; speedup vs baseline: 1.0277x; 1.0277x over previous
//
#include <hip/hip_runtime.h>
#include <stdint.h>

// out[m,p] = sum_k f32(bits(x[m,k]) + bits(weight[p,k]) - OFFSET) + bias[p]
// m=256, n=512, p=512. Pure VALU workload (uint add on bit patterns -> no MFMA).
//
// R2: fix R1's latency-bound inner loop.
//  - 256 blocks x 512 threads = 2048 waves = 2 waves/SIMD (R1 had 1/SIMD).
//  - ds_read_b128 + uint4 x-loads: 4 k per memory instruction.
//  - 64KB LDS tile, 16B-granule XOR swizzle -> conflict-free b128 reads+writes.
//  - register prefetch of next w-tile overlaps global latency with compute.
//  - 4 accumulators break the fadd dependency chain.

#define OFFSET_FP32 1064828928u

constexpr int M = 256;
constexpr int N = 512;
constexpr int P = 512;

constexpr int BM = 4;    // m rows per block (1 per 128-thread group)
constexpr int BP = 128;  // p cols per block
constexpr int KT = 128;  // k tile

__global__ __launch_bounds__(512) void lmul_linear_kernel(
    const uint32_t* __restrict__ xb,   // [M][N] bit patterns of x
    const uint32_t* __restrict__ wb,   // [P][N] bit patterns of weight
    const float*    __restrict__ bias, // [P]
    float*          __restrict__ out)  // [M][P]
{
    // Bs logical [pp][kk], 128x128 words = 64KB (exactly the static limit).
    // 16B granule (4 words) g of row pp lives at word  pp*KT + (g^(pp&7))*4.
    // -> ds_write_b128 staging and ds_read_b128 reads both hit 8 distinct
    //    bank-groups per 8 consecutive lanes: conflict-free, no padding.
    __shared__ uint32_t Bs[BP * KT];

    const int tid     = threadIdx.x;
    const int p_local = tid & (BP - 1);  // 0..127
    const int m_local = tid >> 7;        // 0..3, wave-uniform

    const int p0 = blockIdx.x * BP;
    const int m  = blockIdx.y * BM + m_local;

    const uint32_t* xrow  = xb + (size_t)m * N;        // wave-uniform row
    const uint32_t* wbase = wb + (size_t)p0 * N;

    // staging decomposition: 512 threads = 16 rows x 32 granules per pass, 8 passes
    const int sg  = tid & 31;   // granule within row (16B units), coalesced
    const int sr0 = tid >> 5;   // 0..15

    uint4 stage[8];

    auto load_tile = [&](int k0) {
        #pragma unroll
        for (int ps = 0; ps < 8; ++ps) {
            const int pp = sr0 + ps * 16;
            stage[ps] = *(const uint4*)(wbase + (size_t)pp * N + k0 + sg * 4);
        }
    };
    auto store_tile = [&]() {
        #pragma unroll
        for (int ps = 0; ps < 8; ++ps) {
            const int pp = sr0 + ps * 16;
            const int pg = sg ^ (pp & 7);
            uint4 v = stage[ps];
            // fold the exponent-offset correction in once per (p,k) per block
            v.x -= OFFSET_FP32; v.y -= OFFSET_FP32;
            v.z -= OFFSET_FP32; v.w -= OFFSET_FP32;
            *(uint4*)&Bs[pp * KT + pg * 4] = v;
        }
    };

    float acc0 = 0.f, acc1 = 0.f, acc2 = 0.f, acc3 = 0.f;

    load_tile(0);
    for (int t = 0; t < N / KT; ++t) {
        __syncthreads();            // previous tile's reads complete
        store_tile();
        __syncthreads();            // staging visible
        if (t + 1 < N / KT) load_tile((t + 1) * KT);  // overlaps compute below

        const int k0 = t * KT;
        #pragma unroll 8
        for (int j = 0; j < KT / 4; ++j) {   // 32 steps x 4k
            const uint4 b = *(const uint4*)&Bs[p_local * KT + ((j ^ (p_local & 7)) * 4)];
            const uint4 a = *(const uint4*)(xrow + k0 + j * 4);
            acc0 += __uint_as_float(a.x + b.x);
            acc1 += __uint_as_float(a.y + b.y);
            acc2 += __uint_as_float(a.z + b.z);
            acc3 += __uint_as_float(a.w + b.w);
        }
    }

    const int p = p0 + p_local;
    out[(size_t)m * P + p] = (acc0 + acc1) + (acc2 + acc3) + bias[p];
}

extern "C" void kernel_launch(void* const* d_in, const int* in_sizes, int n_in,
                              void* d_out, int out_size, void* d_ws, size_t ws_size,
                              hipStream_t stream) {
    const uint32_t* xb   = (const uint32_t*)d_in[0];  // x: (256,512) f32 bits
    const uint32_t* wb   = (const uint32_t*)d_in[1];  // weight: (512,512) f32 bits
    const float*    bias = (const float*)d_in[2];     // (512,)
    float*          out  = (float*)d_out;             // (256,512) f32

    dim3 grid(P / BP, M / BM);  // (4, 64) = 256 blocks, 1 per CU
    dim3 block(512);            // 8 waves -> 2 waves/SIMD
    lmul_linear_kernel<<<grid, block, 0, stream>>>(xb, wb, bias, out);
}

// Round 3
// 64.794 us; speedup vs baseline: 1.1218x; 1.0916x over previous
//
#include <hip/hip_runtime.h>
#include <stdint.h>

// out[m,p] = sum_k f32(bits(x[m,k]) + bits(weight[p,k]) - OFFSET) + bias[p]
// m=256, n=512, p=512. Pure VALU workload (uint add on bit patterns -> no MFMA).
//
// R3: make it VALU-bound instead of LDS-bound.
//  - TM=4 m-rows per thread: each b word read from LDS once, used 4x in regs
//    -> LDS traffic/CU drops 1MB -> 256KB (below the 4096-cyc VALU floor).
//  - k-split=4 keeps 512 blocks x 4 waves = 2048 waves = 2 waves/SIMD on all
//    256 CUs despite the 4x thread reduction; partials combined with fp32
//    global atomicAdd (distinct addresses, tolerance covers reordering).
//  - d_out zeroed via hipMemsetAsync on stream (graph-capture legal).
//  - 64KB LDS tile [pp][k], 16B-granule XOR swizzle: 8-lane phases hit 32
//    distinct banks for both ds_write_b128 and ds_read_b128 -> conflict-free.
//  - x-row loads readfirstlane'd -> SMEM pipe, off the VMEM/LDS critical path.

#define OFFSET_FP32 1064828928u

constexpr int M = 256;
constexpr int N = 512;
constexpr int P = 512;

constexpr int BP = 128;     // p cols per block
constexpr int BM = 8;       // m rows per block
constexpr int TM = 4;       // m rows per thread
constexpr int KS = 4;       // k-split factor
constexpr int KT = N / KS;  // 128 k per block

__global__ __launch_bounds__(256) void lmul_linear_kernel(
    const uint32_t* __restrict__ xb,   // [M][N] bit patterns of x
    const uint32_t* __restrict__ wb,   // [P][N] bit patterns of weight
    const float*    __restrict__ bias, // [P]
    float*          __restrict__ out)  // [M][P], pre-zeroed
{
    __shared__ uint32_t Bs[BP * KT];   // 64 KB, row pp at pp*KT, granules XOR-swizzled

    const int tid     = threadIdx.x;
    const int p_local = tid & (BP - 1);                            // 0..127
    const int m_quad  = __builtin_amdgcn_readfirstlane(tid >> 7);  // 0..1, wave-uniform

    const int p0 = blockIdx.y * BP;            // p in grid.y (m fastest for L2 w-tile reuse)
    const int m0 = blockIdx.x * BM + m_quad * TM;
    const int k0 = blockIdx.z * KT;

    // ---- stage w tile [128p][128k] = 64KB: 256 threads x 16 uint4 ----
    const int sg = tid & 31;  // 16B granule within row, coalesced
    const int sr = tid >> 5;  // 0..7
    const uint32_t* wbase = wb + (size_t)p0 * N + k0;
    #pragma unroll
    for (int j = 0; j < 16; ++j) {
        const int pp = sr + j * 8;
        uint4 v = *(const uint4*)(wbase + (size_t)pp * N + sg * 4);
        v.x -= OFFSET_FP32; v.y -= OFFSET_FP32;   // fold offset at staging
        v.z -= OFFSET_FP32; v.w -= OFFSET_FP32;
        const int g = sg ^ (pp & 7);              // swizzle: conflict-free b128 r/w
        *(uint4*)&Bs[pp * KT + g * 4] = v;
    }
    __syncthreads();

    // ---- compute: 32 steps x (1 ds_read_b128 + 4 scalar a-loads + 32 VALU) ----
    const uint32_t* xr0 = xb + (size_t)(m0 + 0) * N + k0;
    const uint32_t* xr1 = xb + (size_t)(m0 + 1) * N + k0;
    const uint32_t* xr2 = xb + (size_t)(m0 + 2) * N + k0;
    const uint32_t* xr3 = xb + (size_t)(m0 + 3) * N + k0;

    float acc[TM][4] = {};
    const uint32_t* brow = &Bs[p_local * KT];
    const int rot = p_local & 7;

    #pragma unroll 8
    for (int j = 0; j < KT / 4; ++j) {
        const uint4 b  = *(const uint4*)&brow[(j ^ rot) * 4];
        const uint4 a0 = *(const uint4*)(xr0 + j * 4);  // wave-uniform -> s_load
        const uint4 a1 = *(const uint4*)(xr1 + j * 4);
        const uint4 a2 = *(const uint4*)(xr2 + j * 4);
        const uint4 a3 = *(const uint4*)(xr3 + j * 4);
        acc[0][0] += __uint_as_float(a0.x + b.x);
        acc[0][1] += __uint_as_float(a0.y + b.y);
        acc[0][2] += __uint_as_float(a0.z + b.z);
        acc[0][3] += __uint_as_float(a0.w + b.w);
        acc[1][0] += __uint_as_float(a1.x + b.x);
        acc[1][1] += __uint_as_float(a1.y + b.y);
        acc[1][2] += __uint_as_float(a1.z + b.z);
        acc[1][3] += __uint_as_float(a1.w + b.w);
        acc[2][0] += __uint_as_float(a2.x + b.x);
        acc[2][1] += __uint_as_float(a2.y + b.y);
        acc[2][2] += __uint_as_float(a2.z + b.z);
        acc[2][3] += __uint_as_float(a2.w + b.w);
        acc[3][0] += __uint_as_float(a3.x + b.x);
        acc[3][1] += __uint_as_float(a3.y + b.y);
        acc[3][2] += __uint_as_float(a3.z + b.z);
        acc[3][3] += __uint_as_float(a3.w + b.w);
    }

    // ---- combine: one k0==0 block per output adds the bias ----
    const int p  = p0 + p_local;
    const float bv = (k0 == 0) ? bias[p] : 0.0f;
    #pragma unroll
    for (int r = 0; r < TM; ++r) {
        const float s = (acc[r][0] + acc[r][1]) + (acc[r][2] + acc[r][3]) + bv;
        atomicAdd(&out[(size_t)(m0 + r) * P + p], s);
    }
}

extern "C" void kernel_launch(void* const* d_in, const int* in_sizes, int n_in,
                              void* d_out, int out_size, void* d_ws, size_t ws_size,
                              hipStream_t stream) {
    const uint32_t* xb   = (const uint32_t*)d_in[0];  // x: (256,512) f32 bits
    const uint32_t* wb   = (const uint32_t*)d_in[1];  // weight: (512,512) f32 bits
    const float*    bias = (const float*)d_in[2];     // (512,)
    float*          out  = (float*)d_out;             // (256,512) f32

    hipMemsetAsync(d_out, 0, (size_t)out_size * sizeof(float), stream);

    dim3 grid(M / BM, P / BP, KS);  // (32, 4, 4) = 512 blocks, 2 per CU
    dim3 block(256);                // 4 waves -> with 2 blocks/CU: 2 waves/SIMD
    lmul_linear_kernel<<<grid, block, 0, stream>>>(xb, wb, bias, out);
}